// Round 18
// baseline (74.667 us; speedup 1.0000x reference)
//
#include <hip/hip_runtime.h>

typedef float f4 __attribute__((ext_vector_type(4)));
typedef float f2 __attribute__((ext_vector_type(2)));

#define PAD 68              // LDS row pitch (floats); 68%32=4 spreads banks
#define NPART 256
#define PART_STRIDE 12288   // 3 * 64*64 floats per block partial

// ws layout (floats):
// [0, 3145728)      partials [256][3][4096]
// [3145728, +256)   bpart (K2)
// [3146240]         uint counter (K2 ticket; reset by K1 block 0)

__device__ __forceinline__ void lds_fence() {
    asm volatile("s_waitcnt lgkmcnt(0)" ::: "memory");
    __builtin_amdgcn_sched_barrier(0);
}

__global__ __launch_bounds__(1024) void fused_gram_kernel(
    const float* __restrict__ p1, const float* __restrict__ p2,
    float* __restrict__ partials, unsigned* __restrict__ cnt)
{
    __shared__ float la[2][8 * PAD];     // double-buffered 8-row tiles, A
    __shared__ float lb[2][8 * PAD];     // and B
    __shared__ unsigned ready[2];        // producer waves done (monotonic)
    __shared__ unsigned normd[2];        // consumer norm waves done
    __shared__ unsigned done[2];         // consumer gram waves done
    const int t  = threadIdx.x;
    const int b  = blockIdx.x >> 5;
    const int oi = blockIdx.x & 31;

    if (blockIdx.x == 0 && t == 0) *cnt = 0u;   // reset K2 ticket each call
    if (t < 2) { ready[t] = 0u; normd[t] = 0u; done[t] = 0u; }
    // one block-wide barrier before any flag use (raw: keep vmem free)
    asm volatile("s_waitcnt lgkmcnt(0)" ::: "memory");
    __builtin_amdgcn_s_barrier();
    __builtin_amdgcn_sched_barrier(0);

    const int wave = t >> 6;
    const int lane = t & 63;

    if (wave < 8) {
        // ================= PRODUCERS: stream + pool, never block on compute
        const int pt  = t;               // 0..511
        const int m   = pt >> 8;         // input
        const int pm  = pt & 255;
        const int cl  = pm >> 3;         // channel low (0..31); also cl+32
        const int oj8 = pm & 7;
        const float* src = m ? p2 : p1;
        const long base0 = (long)((b * 64 + cl     ) * 128 + oi * 4) * 128 + oj8 * 4;
        const long base1 = (long)((b * 64 + cl + 32) * 128 + oi * 4) * 128 + oj8 * 4;
        float* dst[2] = { (m ? lb[0] : la[0]), (m ? lb[1] : la[1]) };

        f4 X[8], Y[8];
        auto issue = [&](int q, f4* R) {
            const float* s0 = src + base0 + q * 32;
            const float* s1 = src + base1 + q * 32;
            R[0] = *(const f4*)(s0);       R[1] = *(const f4*)(s0 + 128);
            R[2] = *(const f4*)(s0 + 256); R[3] = *(const f4*)(s0 + 384);
            R[4] = *(const f4*)(s1);       R[5] = *(const f4*)(s1 + 128);
            R[6] = *(const f4*)(s1 + 256); R[7] = *(const f4*)(s1 + 384);
        };
        auto pool = [&](const f4* R, int buf) {
            const f4 v0 = (R[0] + R[1]) + (R[2] + R[3]);
            const f4 v1 = (R[4] + R[5]) + (R[6] + R[7]);
            dst[buf][oj8 * PAD + cl]      = ((v0[0]+v0[1])+(v0[2]+v0[3])) * 0.0625f;
            dst[buf][oj8 * PAD + cl + 32] = ((v1[0]+v1[1])+(v1[2]+v1[3])) * 0.0625f;
        };
        auto mark = [&](int buf) {
            lds_fence();                 // pool writes complete before flag
            if (lane == 0)
                __hip_atomic_fetch_add(&ready[buf], 1u, __ATOMIC_RELAXED,
                                       __HIP_MEMORY_SCOPE_WORKGROUP);
        };
        auto wait_done = [&](int buf, unsigned tgt) {
            while (__hip_atomic_load(&done[buf], __ATOMIC_RELAXED,
                                     __HIP_MEMORY_SCOPE_WORKGROUP) < tgt)
                __builtin_amdgcn_s_sleep(1);
            __builtin_amdgcn_sched_barrier(0);
        };

        issue(0, X); issue(1, Y);
        pool(X, 0);  issue(2, X);  mark(0);           // q=0
        pool(Y, 1);  issue(3, Y);  mark(1);           // q=1
        wait_done(0, 8);  pool(X, 0);  mark(0);       // q=2 (ready[0]->16)
        wait_done(1, 8);  pool(Y, 1);  mark(1);       // q=3 (ready[1]->16)
        return;                                        // producers exit
    }

    // ================= CONSUMERS: norm + gram, never touch global input
    const int ct = t - 512;              // 0..511
    const int cw = ct >> 6;              // consumer wave 0..7; norms row cw
    const int c1 = (ct >> 4) * 2;        // gram tile rows c1,c1+1
    const int c2 = (ct & 15) * 4;        // gram tile cols c2..c2+3
    f4 aa[2] = {}; f4 ab[2] = {}; f4 bb[2] = {};

    auto wait_flag = [&](unsigned* f, unsigned tgt) {
        while (__hip_atomic_load(f, __ATOMIC_RELAXED,
                                 __HIP_MEMORY_SCOPE_WORKGROUP) < tgt)
            __builtin_amdgcn_s_sleep(1);
        __builtin_amdgcn_sched_barrier(0);
    };

    #pragma unroll
    for (int q = 0; q < 4; ++q) {
        const int buf = q & 1;
        const unsigned rp = (unsigned)(q >> 1) + 1u;   // round target mult
        wait_flag(&ready[buf], 8u * rp);

        // norm: wave cw rescales row cw of A and of B (in place)
        {
            float* rA = la[buf] + cw * PAD;
            float* rB = lb[buf] + cw * PAD;
            const float va = rA[lane], vb = rB[lane];
            float sa = va * va, sb = vb * vb;
            sa += __shfl_xor(sa, 1);   sb += __shfl_xor(sb, 1);
            sa += __shfl_xor(sa, 2);   sb += __shfl_xor(sb, 2);
            sa += __shfl_xor(sa, 4);   sb += __shfl_xor(sb, 4);
            sa += __shfl_xor(sa, 8);   sb += __shfl_xor(sb, 8);
            sa += __shfl_xor(sa, 16);  sb += __shfl_xor(sb, 16);
            sa += __shfl_xor(sa, 32);  sb += __shfl_xor(sb, 32);
            rA[lane] = va * (1.0f / fmaxf(sqrtf(sa), 1e-8f));
            rB[lane] = vb * (1.0f / fmaxf(sqrtf(sb), 1e-8f));
        }
        lds_fence();
        if (lane == 0)
            __hip_atomic_fetch_add(&normd[buf], 1u, __ATOMIC_RELAXED,
                                   __HIP_MEMORY_SCOPE_WORKGROUP);
        wait_flag(&normd[buf], 8u * rp);

        // gram: 2x4 tile over this buffer's 8 rows
        #pragma unroll
        for (int r = 0; r < 8; ++r) {
            const f2 a1 = *(const f2*)&la[buf][r * PAD + c1];
            const f4 a2 = *(const f4*)&la[buf][r * PAD + c2];
            const f2 b1 = *(const f2*)&lb[buf][r * PAD + c1];
            const f4 b2 = *(const f4*)&lb[buf][r * PAD + c2];
            aa[0] += a2 * a1[0];  aa[1] += a2 * a1[1];
            ab[0] += b2 * a1[0];  ab[1] += b2 * a1[1];
            bb[0] += b2 * b1[0];  bb[1] += b2 * b1[1];
        }
        lds_fence();                     // reads done before release
        if (lane == 0)
            __hip_atomic_fetch_add(&done[buf], 1u, __ATOMIC_RELAXED,
                                   __HIP_MEMORY_SCOPE_WORKGROUP);
    }

    // ---- partial store (consumers own the whole [3][64][64] tile set)
    float* P = partials + (long)blockIdx.x * PART_STRIDE;
    #pragma unroll
    for (int i = 0; i < 2; ++i) {
        *(f4*)&P[0 * 4096 + (c1 + i) * 64 + c2] = aa[i];
        *(f4*)&P[1 * 4096 + (c1 + i) * 64 + c2] = ab[i];
        *(f4*)&P[2 * 4096 + (c1 + i) * 64 + c2] = bb[i];
    }
}

// K2: byte-identical to round 3's (best measured): 256 blocks x 256 threads.
__global__ __launch_bounds__(256) void reduce_kernel(
    const float* __restrict__ partials, float* __restrict__ bpart,
    unsigned* __restrict__ cnt, float* __restrict__ out)
{
    __shared__ float red[3][16][17];
    __shared__ float vred[16];
    __shared__ float fr[256];
    __shared__ unsigned last_flag;
    const int t  = threadIdx.x;
    const int el = t & 15;
    const int pc = t >> 4;
    const int e  = blockIdx.x * 16 + el;

    float saa = 0.f, sab = 0.f, sbb = 0.f;
    #pragma unroll 4
    for (int i = 0; i < 16; ++i) {
        const float* P = partials + (long)(pc * 16 + i) * PART_STRIDE;
        saa += P[e];
        sab += P[4096 + e];
        sbb += P[8192 + e];
    }
    red[0][el][pc] = saa; red[1][el][pc] = sab; red[2][el][pc] = sbb;
    __syncthreads();

    if (t < 16) {
        float a = 0.f, mm = 0.f, bv = 0.f;
        #pragma unroll
        for (int p = 0; p < 16; ++p) {
            a  += red[0][t][p];
            mm += red[1][t][p];
            bv += red[2][t][p];
        }
        vred[t] = fmaf(a, a, fmaf(bv, bv, -2.0f * (mm * mm)));
    }
    __syncthreads();

    if (t == 0) {
        float s = 0.f;
        #pragma unroll
        for (int i = 0; i < 16; ++i) s += vred[i];
        __hip_atomic_store(&bpart[blockIdx.x], s, __ATOMIC_RELEASE,
                           __HIP_MEMORY_SCOPE_AGENT);
        unsigned old = __hip_atomic_fetch_add(cnt, 1u, __ATOMIC_ACQ_REL,
                                              __HIP_MEMORY_SCOPE_AGENT);
        last_flag = (old == NPART - 1) ? 1u : 0u;
    }
    __syncthreads();

    if (last_flag) {   // block-uniform
        fr[t] = __hip_atomic_load(&bpart[t], __ATOMIC_ACQUIRE,
                                  __HIP_MEMORY_SCOPE_AGENT);
        __syncthreads();
        for (int s2 = 128; s2 > 0; s2 >>= 1) {
            if (t < s2) fr[t] += fr[t + s2];
            __syncthreads();
        }
        if (t == 0) out[0] = fr[0] * (1.0f / 67108864.0f);  // / 8192^2
    }
}

extern "C" void kernel_launch(void* const* d_in, const int* in_sizes, int n_in,
                              void* d_out, int out_size, void* d_ws, size_t ws_size,
                              hipStream_t stream)
{
    const float* p1 = (const float*)d_in[0];
    const float* p2 = (const float*)d_in[1];
    float* ws       = (float*)d_ws;
    float* partials = ws;                                  // 256*12288
    float* bpart    = ws + (long)NPART * PART_STRIDE;      // 256
    unsigned* cnt   = (unsigned*)(ws + 3146240);           // 1

    fused_gram_kernel<<<NPART, 1024, 0, stream>>>(p1, p2, partials, cnt);
    reduce_kernel   <<<NPART, 256, 0, stream>>>(partials, bpart, cnt, (float*)d_out);
}

// Round 19
// 40.290 us; speedup vs baseline: 1.8532x; 1.8532x over previous
//
#include <hip/hip_runtime.h>

typedef float f4 __attribute__((ext_vector_type(4)));
typedef float f2 __attribute__((ext_vector_type(2)));

#define PAD 68              // LDS row pitch (floats); 68%32=4 spreads banks
#define NPART 512           // gram blocks = partial count (2 blocks/CU)
#define PART_STRIDE 12288   // 3 * 64*64 floats per block partial
#define NBLK2 256           // reduce-kernel blocks

// ws layout (floats):
// [0, 6291456)      partials [512][3][4096]  (25.2 MB)
// [6291456, +256)   bpart (K2)
// [6292224]         uint counter (K2 ticket; reset by K1 block 0)

// Barrier that does NOT drain outstanding global loads (prefetch survives):
// LDS ordering via lgkmcnt(0), then raw s_barrier; sched_barrier pins code
// motion so later ds ops can't hoist above the barrier.
__device__ __forceinline__ void lds_barrier() {
    asm volatile("s_waitcnt lgkmcnt(0)" ::: "memory");
    __builtin_amdgcn_s_barrier();
    __builtin_amdgcn_sched_barrier(0);
}

__global__ __launch_bounds__(512) void fused_gram_kernel(
    const float* __restrict__ p1, const float* __restrict__ p2,
    float* __restrict__ partials, unsigned* __restrict__ cnt)
{
    __shared__ float la[2][4 * PAD];   // double-buffered 4-row tiles, input A
    __shared__ float lb[2][4 * PAD];   // and input B
    const int t   = threadIdx.x;
    const int blk = blockIdx.x;        // 0..511
    const int b   = blk >> 6;          // batch 0..7
    const int oi  = (blk >> 1) & 31;   // pooled row strip 0..31
    const int h   = blk & 1;           // pooled-column half 0/1 (oj base h*16)

    if (blk == 0 && t == 0) *cnt = 0u;   // reset K2 ticket each call

    // --- per-thread pool slot: (m, c, oj4) ---
    const int m   = t >> 8;            // input select 0/1
    const int c   = (t >> 2) & 63;     // channel
    const int oj4 = t & 3;             // row within 4-row sub
    const float* src = m ? p2 : p1;
    // col offset = (h*16 + q*4 + oj4) * 4 floats; q contributes +16 per sub
    const long base = (long)((b * 64 + c) * 128 + oi * 4) * 128
                    + h * 64 + oj4 * 4;
    float* dst0 = m ? lb[0] : la[0];
    float* dst1 = m ? lb[1] : la[1];

    // --- norm-wave assignment: wave w owns row (nm, nr), lane = channel ---
    const int l  = t & 63;
    const int w  = t >> 6;             // 8 waves
    const int nm = w >> 2, nr = w & 3;

    // --- gram 2x4 tile: rows c1,c1+1; cols c2..c2+3 ---
    const int c1 = (t >> 4) * 2;
    const int c2 = (t & 15) * 4;
    f4 aa0 = {}, aa1 = {}, ab0 = {}, ab1 = {}, bb0 = {}, bb1 = {};

    auto issue = [&](int q, f4& R0, f4& R1, f4& R2, f4& R3) {
        const float* s = src + base + q * 16;
        R0 = *(const f4*)(s);
        R1 = *(const f4*)(s + 128);
        R2 = *(const f4*)(s + 256);
        R3 = *(const f4*)(s + 384);
    };
    auto pool = [&](const f4& R0, const f4& R1, const f4& R2, const f4& R3,
                    float* dst) {
        const f4 v = (R0 + R1) + (R2 + R3);
        dst[oj4 * PAD + c] = ((v[0] + v[1]) + (v[2] + v[3])) * 0.0625f;
    };
    auto normphase = [&](int bi) {     // 8 waves: reduce + rescale in place
        float* rowp = (nm ? lb[bi] : la[bi]) + nr * PAD;
        const float v = rowp[l];
        float ss = v * v;
        ss += __shfl_xor(ss, 1);
        ss += __shfl_xor(ss, 2);
        ss += __shfl_xor(ss, 4);
        ss += __shfl_xor(ss, 8);
        ss += __shfl_xor(ss, 16);
        ss += __shfl_xor(ss, 32);
        rowp[l] = v * (1.0f / fmaxf(sqrtf(ss), 1e-8f));
    };
    auto gram = [&](int bi) {
        #pragma unroll
        for (int r = 0; r < 4; ++r) {
            const f2 a1 = *(const f2*)&la[bi][r * PAD + c1];
            const f4 a2 = *(const f4*)&la[bi][r * PAD + c2];
            const f2 b1 = *(const f2*)&lb[bi][r * PAD + c1];
            const f4 b2 = *(const f4*)&lb[bi][r * PAD + c2];
            aa0 += a2 * a1[0];  aa1 += a2 * a1[1];
            ab0 += b2 * a1[0];  ab1 += b2 * a1[1];
            bb0 += b2 * b1[0];  bb1 += b2 * b1[1];
        }
    };

    // ---- software pipeline, depth 2 (r11-identical schedule, halved dims)
    f4 A0, A1, A2, A3, B0, B1, B2, B3;
    issue(0, A0, A1, A2, A3);
    issue(1, B0, B1, B2, B3);

    pool(A0, A1, A2, A3, dst0);  issue(2, A0, A1, A2, A3);
    lds_barrier();  normphase(0);  lds_barrier();  gram(0);

    pool(B0, B1, B2, B3, dst1);  issue(3, B0, B1, B2, B3);
    lds_barrier();  normphase(1);  lds_barrier();  gram(1);

    pool(A0, A1, A2, A3, dst0);
    lds_barrier();  normphase(0);  lds_barrier();  gram(0);

    pool(B0, B1, B2, B3, dst1);
    lds_barrier();  normphase(1);  lds_barrier();  gram(1);

    // ---- partial store: [blk][3][4096], f4 rows ----
    float* P = partials + (long)blk * PART_STRIDE;
    *(f4*)&P[0 * 4096 + (c1    ) * 64 + c2] = aa0;
    *(f4*)&P[0 * 4096 + (c1 + 1) * 64 + c2] = aa1;
    *(f4*)&P[1 * 4096 + (c1    ) * 64 + c2] = ab0;
    *(f4*)&P[1 * 4096 + (c1 + 1) * 64 + c2] = ab1;
    *(f4*)&P[2 * 4096 + (c1    ) * 64 + c2] = bb0;
    *(f4*)&P[2 * 4096 + (c1 + 1) * 64 + c2] = bb1;
}

// K2: r8-validated 512-partial variant: 256 blocks x 256 threads.
__global__ __launch_bounds__(256) void reduce_kernel(
    const float* __restrict__ partials, float* __restrict__ bpart,
    unsigned* __restrict__ cnt, float* __restrict__ out)
{
    __shared__ float red[3][16][17];
    __shared__ float vred[16];
    __shared__ float fr[256];
    __shared__ unsigned last_flag;
    const int t  = threadIdx.x;
    const int el = t & 15;       // entry within block
    const int pc = t >> 4;       // partial chunk 0..15 (32 partials each)
    const int e  = blockIdx.x * 16 + el;

    float saa = 0.f, sab = 0.f, sbb = 0.f;
    #pragma unroll 4
    for (int i = 0; i < 32; ++i) {
        const float* P = partials + (long)(pc * 32 + i) * PART_STRIDE;
        saa += P[e];
        sab += P[4096 + e];
        sbb += P[8192 + e];
    }
    red[0][el][pc] = saa; red[1][el][pc] = sab; red[2][el][pc] = sbb;
    __syncthreads();

    if (t < 16) {
        float a = 0.f, mm = 0.f, bv = 0.f;
        #pragma unroll
        for (int p = 0; p < 16; ++p) {
            a  += red[0][t][p];
            mm += red[1][t][p];
            bv += red[2][t][p];
        }
        vred[t] = fmaf(a, a, fmaf(bv, bv, -2.0f * (mm * mm)));
    }
    __syncthreads();

    if (t == 0) {
        float s = 0.f;
        #pragma unroll
        for (int i = 0; i < 16; ++i) s += vred[i];
        __hip_atomic_store(&bpart[blockIdx.x], s, __ATOMIC_RELEASE,
                           __HIP_MEMORY_SCOPE_AGENT);
        unsigned old = __hip_atomic_fetch_add(cnt, 1u, __ATOMIC_ACQ_REL,
                                              __HIP_MEMORY_SCOPE_AGENT);
        last_flag = (old == NBLK2 - 1) ? 1u : 0u;
    }
    __syncthreads();

    if (last_flag) {   // block-uniform
        fr[t] = __hip_atomic_load(&bpart[t], __ATOMIC_ACQUIRE,
                                  __HIP_MEMORY_SCOPE_AGENT);
        __syncthreads();
        for (int s2 = 128; s2 > 0; s2 >>= 1) {
            if (t < s2) fr[t] += fr[t + s2];
            __syncthreads();
        }
        if (t == 0) out[0] = fr[0] * (1.0f / 67108864.0f);  // / 8192^2
    }
}

extern "C" void kernel_launch(void* const* d_in, const int* in_sizes, int n_in,
                              void* d_out, int out_size, void* d_ws, size_t ws_size,
                              hipStream_t stream)
{
    const float* p1 = (const float*)d_in[0];
    const float* p2 = (const float*)d_in[1];
    float* ws       = (float*)d_ws;
    float* partials = ws;                                  // 512*12288
    float* bpart    = ws + (long)NPART * PART_STRIDE;      // 256
    unsigned* cnt   = (unsigned*)(ws + 6292224);           // 1

    fused_gram_kernel<<<NPART, 512, 0, stream>>>(p1, p2, partials, cnt);
    reduce_kernel   <<<NBLK2, 256, 0, stream>>>(partials, bpart, cnt, (float*)d_out);
}